// Round 6
// baseline (320.067 us; speedup 1.0000x reference)
//
#include <hip/hip_runtime.h>
#include <math.h>

// Problem constants (from reference setup_inputs)
#define B 64
#define S 2048
#define H 1024
#define SPLIT 16
#define RPB (S / SPLIT)    // 128 rows per block
#define THREADS 256
#define WAVES 4
#define RPW (RPB / WAVES)  // 32 rows per wave

// ---------------------------------------------------------------------------
// Single kernel, no grid sync (cooperative launch fails under graph capture
// in this harness — R5). Cross-block combine uses the device-scope-atomic
// "last block finalizes" pattern (guide G12/G16).
//
// Phase 1 (R1's proven structure): block (b,sp) streams its 128 enc rows once,
//   score + online-softmax context accumulation; writes raw scores to attn,
//   partial (M,Z,ctx[H]) to ws. Then __threadfence() + agent-scope
//   fetch_add(cnt[b]); the 16th arriver finalizes batch b.
// Phase 2 (finalizer block only): merge 16 partials -> context[b][0..H),
//   normalize attn[b][0..S). Overlaps with other batches' phase 1.
// ---------------------------------------------------------------------------
__global__ __launch_bounds__(THREADS)
void luong_fused(const float* __restrict__ dec_h,
                 const float* __restrict__ dec_c,
                 const float* __restrict__ enc,
                 float* __restrict__ ctx_out,    // d_out, [B][H]
                 float* __restrict__ attn,       // d_out + B*H, [B][S]
                 float* __restrict__ ctx_part,   // ws: [B][SPLIT][H]
                 float* __restrict__ mz_part,    // ws: [B][SPLIT][2]
                 unsigned* __restrict__ cnt) {   // ws: [B], zeroed per launch
  const int bid  = blockIdx.x;
  const int b    = bid / SPLIT;
  const int sp   = bid % SPLIT;
  const int t    = threadIdx.x;
  const int w    = t >> 6;     // wave id 0..3
  const int lane = t & 63;

  // ---- phase 1: fused score + online-softmax context (R1 structure) ----
  float4 dec[4];
  {
    const float4* dh = (const float4*)(dec_h + (size_t)b * H);
    const float4* dc = (const float4*)(dec_c + (size_t)b * H);
#pragma unroll
    for (int c = 0; c < 4; ++c) {
      float4 a  = dh[c * 64 + lane];
      float4 bb = dc[c * 64 + lane];
      dec[c] = make_float4(a.x + bb.x, a.y + bb.y, a.z + bb.z, a.w + bb.w);
    }
  }

  float m = -INFINITY;
  float Z = 0.f;
  float ctx[16];
#pragma unroll
  for (int k = 0; k < 16; ++k) ctx[k] = 0.f;

  const int s_base = sp * RPB + w;
  const float4* ebase = (const float4*)(enc + ((size_t)b * S + s_base) * H);

  for (int r = 0; r < RPW; ++r) {
    const float4* rp = ebase + (size_t)r * (WAVES * (H / 4));
    float4 e[4];
#pragma unroll
    for (int c = 0; c < 4; ++c) e[c] = rp[c * 64 + lane];

    float p = 0.f;
#pragma unroll
    for (int c = 0; c < 4; ++c)
      p += e[c].x * dec[c].x + e[c].y * dec[c].y +
           e[c].z * dec[c].z + e[c].w * dec[c].w;
#pragma unroll
    for (int off = 32; off >= 1; off >>= 1)
      p += __shfl_xor(p, off, 64);

    if (lane == 0) attn[b * S + s_base + r * WAVES] = p;  // raw score

    if (p > m) {  // wave-uniform branch
      const float f = expf(m - p);
      Z *= f;
#pragma unroll
      for (int k = 0; k < 16; ++k) ctx[k] *= f;
      m = p;
    }
    const float e_ = expf(p - m);
    Z += e_;
#pragma unroll
    for (int c = 0; c < 4; ++c) {
      ctx[c * 4 + 0] += e_ * e[c].x;
      ctx[c * 4 + 1] += e_ * e[c].y;
      ctx[c * 4 + 2] += e_ * e[c].z;
      ctx[c * 4 + 3] += e_ * e[c].w;
    }
  }

  // ---- combine the 4 waves of this block via LDS ----
  __shared__ float ctx_lds[WAVES][H];  // 16 KiB
  __shared__ float mzs[WAVES][2];
#pragma unroll
  for (int c = 0; c < 4; ++c) {
    float4 v = make_float4(ctx[c * 4 + 0], ctx[c * 4 + 1],
                           ctx[c * 4 + 2], ctx[c * 4 + 3]);
    ((float4*)&ctx_lds[w][c * 256])[lane] = v;
  }
  if (lane == 0) { mzs[w][0] = m; mzs[w][1] = Z; }
  __syncthreads();

  {
    const float Mb = fmaxf(fmaxf(mzs[0][0], mzs[1][0]),
                           fmaxf(mzs[2][0], mzs[3][0]));
    float fac[WAVES];
    float Zb = 0.f;
#pragma unroll
    for (int i = 0; i < WAVES; ++i) {
      fac[i] = expf(mzs[i][0] - Mb);
      Zb += mzs[i][1] * fac[i];
    }
    float* outp = ctx_part + ((size_t)b * SPLIT + sp) * H;
#pragma unroll
    for (int q = 0; q < 4; ++q) {
      const int h = q * 256 + t;
      float v = 0.f;
#pragma unroll
      for (int i = 0; i < WAVES; ++i) v += ctx_lds[i][h] * fac[i];
      outp[h] = v;
    }
    if (t == 0) {
      mz_part[(b * SPLIT + sp) * 2 + 0] = Mb;
      mz_part[(b * SPLIT + sp) * 2 + 1] = Zb;
    }
  }

  // ---- arrival: device-scope release; last arriver finalizes batch b ----
  __threadfence();  // make this block's ws/attn writes device-visible
  __shared__ unsigned last;
  if (t == 0) {
    unsigned old = __hip_atomic_fetch_add(&cnt[b], 1u,
                                          __ATOMIC_ACQ_REL,
                                          __HIP_MEMORY_SCOPE_AGENT);
    last = (old == SPLIT - 1) ? 1u : 0u;
  }
  __syncthreads();
  if (!last) return;
  __threadfence();  // acquire side: invalidate caches before reading peers' data

  // ---- phase 2: finalize batch b (this block only) ----
  const float* mzb = mz_part + (size_t)b * SPLIT * 2;
  float M = -INFINITY;
#pragma unroll
  for (int i = 0; i < SPLIT; ++i) M = fmaxf(M, mzb[2 * i]);
  float fac[SPLIT];
  float Zt = 0.f;
#pragma unroll
  for (int i = 0; i < SPLIT; ++i) {
    fac[i] = expf(mzb[2 * i] - M);
    Zt += mzb[2 * i + 1] * fac[i];
  }
  const float invZ = 1.f / Zt;

  // context: 1024 elems, 4 per thread, coalesced
#pragma unroll
  for (int q = 0; q < 4; ++q) {
    const int h = q * 256 + t;
    float v = 0.f;
#pragma unroll
    for (int i = 0; i < SPLIT; ++i)
      v += ctx_part[((size_t)b * SPLIT + i) * H + h] * fac[i];
    ctx_out[(size_t)b * H + h] = v * invZ;
  }

  // attention weights: 2048 elems, 8 per thread, coalesced
#pragma unroll
  for (int k = 0; k < 8; ++k) {
    const size_t idx = (size_t)b * S + k * 256 + t;
    attn[idx] = expf(attn[idx] - M) * invZ;
  }
}

extern "C" void kernel_launch(void* const* d_in, const int* in_sizes, int n_in,
                              void* d_out, int out_size, void* d_ws, size_t ws_size,
                              hipStream_t stream) {
  const float* dec_h = (const float*)d_in[0];
  const float* dec_c = (const float*)d_in[1];
  const float* enc   = (const float*)d_in[2];

  float* ctx_out = (float*)d_out;            // [B][H]
  float* attn    = (float*)d_out + B * H;    // [B][S]

  float*    ctx_part = (float*)d_ws;                        // B*SPLIT*H floats = 4 MiB
  float*    mz_part  = ctx_part + (size_t)B * SPLIT * H;    // B*SPLIT*2
  unsigned* cnt      = (unsigned*)(mz_part + (size_t)B * SPLIT * 2);  // B

  hipMemsetAsync(cnt, 0, B * sizeof(unsigned), stream);
  luong_fused<<<B * SPLIT, THREADS, 0, stream>>>(dec_h, dec_c, enc,
                                                 ctx_out, attn,
                                                 ctx_part, mz_part, cnt);
}

// Round 7
// 102.353 us; speedup vs baseline: 3.1271x; 3.1271x over previous
//
#include <hip/hip_runtime.h>
#include <math.h>

// Problem constants (from reference setup_inputs)
#define B 64
#define S 2048
#define H 1024
#define SPLIT 16
#define ROWS_PER_BLOCK (S / SPLIT)              // 128
#define THREADS 256
#define WAVES 4
#define ROWS_PER_WAVE (ROWS_PER_BLOCK / WAVES)  // 32

// ---------------------------------------------------------------------------
// Pass 1: fused score + online-softmax context accumulation.
// VERBATIM the R1 kernel (proven 114.6 us total; ~5.3 TB/s effective).
// Do NOT append tail code here — R6 showed the combined allocation drops
// VGPR to 40 (< the 48 live floats) and the loop becomes remat/spill-bound
// (757 GB/s, VALUBusy 3.7%).
// ---------------------------------------------------------------------------
__global__ __launch_bounds__(THREADS)
void luong_pass1(const float* __restrict__ dec_h,
                 const float* __restrict__ dec_c,
                 const float* __restrict__ enc,
                 float* __restrict__ attn_raw,   // d_out + B*H, raw scores
                 float* __restrict__ ctx_part,   // [B][SPLIT][H]
                 float* __restrict__ mz_part) {  // [B][SPLIT][2]
  const int bid  = blockIdx.x;
  const int b    = bid / SPLIT;
  const int sp   = bid % SPLIT;
  const int t    = threadIdx.x;
  const int w    = t >> 6;     // wave id 0..3
  const int lane = t & 63;

  // dec = dec_h + dec_c, distributed 16 elems per lane (same for all waves)
  float4 dec[4];
  const float4* dh = (const float4*)(dec_h + (size_t)b * H);
  const float4* dc = (const float4*)(dec_c + (size_t)b * H);
#pragma unroll
  for (int c = 0; c < 4; ++c) {
    float4 a  = dh[c * 64 + lane];
    float4 bb = dc[c * 64 + lane];
    dec[c] = make_float4(a.x + bb.x, a.y + bb.y, a.z + bb.z, a.w + bb.w);
  }

  float m = -INFINITY;
  float Z = 0.f;
  float ctx[16];
#pragma unroll
  for (int k = 0; k < 16; ++k) ctx[k] = 0.f;

  const int s_base = sp * ROWS_PER_BLOCK + w;
  for (int r = 0; r < ROWS_PER_WAVE; ++r) {
    const int s = s_base + r * WAVES;
    const float4* erow = (const float4*)(enc + ((size_t)b * S + s) * H);
    float4 e[4];
#pragma unroll
    for (int c = 0; c < 4; ++c) e[c] = erow[c * 64 + lane];

    // score = <enc_row, dec>
    float partial = 0.f;
#pragma unroll
    for (int c = 0; c < 4; ++c)
      partial += e[c].x * dec[c].x + e[c].y * dec[c].y +
                 e[c].z * dec[c].z + e[c].w * dec[c].w;
#pragma unroll
    for (int off = 32; off >= 1; off >>= 1)
      partial += __shfl_xor(partial, off, 64);
    const float score = partial;  // all 64 lanes hold it

    if (lane == 0) attn_raw[b * S + s] = score;  // raw score; fixed up later

    // online softmax update (wave-uniform branch)
    if (score > m) {
      const float f = expf(m - score);
      Z *= f;
#pragma unroll
      for (int k = 0; k < 16; ++k) ctx[k] *= f;
      m = score;
    }
    const float p = expf(score - m);
    Z += p;
#pragma unroll
    for (int c = 0; c < 4; ++c) {
      ctx[c * 4 + 0] += p * e[c].x;
      ctx[c * 4 + 1] += p * e[c].y;
      ctx[c * 4 + 2] += p * e[c].z;
      ctx[c * 4 + 3] += p * e[c].w;
    }
  }

  // ---- combine the 4 waves of this block via LDS ----
  __shared__ float ctx_lds[WAVES][H];  // 16 KiB
  __shared__ float mzs[WAVES][2];
#pragma unroll
  for (int c = 0; c < 4; ++c) {
    float4 v = make_float4(ctx[c * 4 + 0], ctx[c * 4 + 1],
                           ctx[c * 4 + 2], ctx[c * 4 + 3]);
    ((float4*)&ctx_lds[w][c * 256])[lane] = v;
  }
  if (lane == 0) { mzs[w][0] = m; mzs[w][1] = Z; }
  __syncthreads();

  const float M = fmaxf(fmaxf(mzs[0][0], mzs[1][0]),
                        fmaxf(mzs[2][0], mzs[3][0]));
  float fac[WAVES];
  float Zb = 0.f;
#pragma unroll
  for (int i = 0; i < WAVES; ++i) {
    fac[i] = expf(mzs[i][0] - M);
    Zb += mzs[i][1] * fac[i];
  }

  float* outp = ctx_part + ((size_t)b * SPLIT + sp) * H;
#pragma unroll
  for (int q = 0; q < 4; ++q) {
    const int h = q * 256 + t;
    float v = 0.f;
#pragma unroll
    for (int i = 0; i < WAVES; ++i) v += ctx_lds[i][h] * fac[i];
    outp[h] = v;
  }
  if (t == 0) {
    mz_part[(b * SPLIT + sp) * 2 + 0] = M;
    mz_part[(b * SPLIT + sp) * 2 + 1] = Zb;
  }
}

// ---------------------------------------------------------------------------
// Fused tail: ONE kernel, grid = B*4 = 256 blocks (1/CU). Block (b, q4):
//   - redundantly merges the 16 tiny (M,Z) partials (32 floats, L2-hot)
//   - writes its quarter of context[b] (256 elems, 16-partial weighted sum)
//   - normalizes its quarter of attn[b] (512 elems, in-place)
// Replaces the two serial tail kernels (combine 64-block + fixup) + one
// launch gap.
// ---------------------------------------------------------------------------
__global__ __launch_bounds__(256)
void luong_tail(const float* __restrict__ ctx_part,
                const float* __restrict__ mz_part,
                float* __restrict__ ctx_out,   // d_out, [B][H]
                float* __restrict__ attn) {    // d_out + B*H, raw -> weights
  const int b  = blockIdx.x >> 2;
  const int q4 = blockIdx.x & 3;
  const int t  = threadIdx.x;

  const float* mz = mz_part + (size_t)b * SPLIT * 2;

  float M = -INFINITY;
#pragma unroll
  for (int i = 0; i < SPLIT; ++i) M = fmaxf(M, mz[2 * i]);
  float fac[SPLIT];
  float Z = 0.f;
#pragma unroll
  for (int i = 0; i < SPLIT; ++i) {
    fac[i] = expf(mz[2 * i] - M);
    Z += mz[2 * i + 1] * fac[i];
  }
  const float invZ = 1.f / Z;

  // context quarter: h = q4*256 + t (coalesced per partial; ctx_part is L2/L3-hot)
  {
    const int h = q4 * 256 + t;
    float v = 0.f;
#pragma unroll
    for (int i = 0; i < SPLIT; ++i)
      v += ctx_part[((size_t)b * SPLIT + i) * H + h] * fac[i];
    ctx_out[(size_t)b * H + h] = v * invZ;
  }

  // attn quarter: s in [q4*512, q4*512 + 512), in-place normalize
#pragma unroll
  for (int k = 0; k < 2; ++k) {
    const int s = q4 * 512 + k * 256 + t;
    const size_t idx = (size_t)b * S + s;
    attn[idx] = expf(attn[idx] - M) * invZ;
  }
}

extern "C" void kernel_launch(void* const* d_in, const int* in_sizes, int n_in,
                              void* d_out, int out_size, void* d_ws, size_t ws_size,
                              hipStream_t stream) {
  const float* dec_h = (const float*)d_in[0];
  const float* dec_c = (const float*)d_in[1];
  const float* enc   = (const float*)d_in[2];

  float* ctx_out = (float*)d_out;            // [B][H]
  float* attn    = (float*)d_out + B * H;    // [B][S]

  float* ctx_part = (float*)d_ws;                       // B*SPLIT*H floats = 4 MiB
  float* mz_part  = ctx_part + (size_t)B * SPLIT * H;   // B*SPLIT*2

  luong_pass1<<<B * SPLIT, THREADS, 0, stream>>>(dec_h, dec_c, enc, attn,
                                                 ctx_part, mz_part);
  luong_tail<<<B * 4, 256, 0, stream>>>(ctx_part, mz_part, ctx_out, attn);
}